// Round 2
// baseline (945.066 us; speedup 1.0000x reference)
//
#include <hip/hip_runtime.h>

// B=64, IN=1024, OUT=1024, T=256
// syn[b,o,t] = sum_i W[o,i] * x[b,i,t]  -- accumulated in f64 (exact products:
// f32*f32 fits in f64). Stored as double-f32 (hi in d_out, lo in d_ws).
// Scan (leaky integrate-and-fire) runs in f64 from hi+lo, writes f32 spikes
// into d_out in place.
//
// Rationale: output is binary; f32 GEMM summation-order noise (~2e-6) flips
// ~6 spikes out of 16.7M vs the reference. f64 accumulation puts us within
// ~2^-48 relative of the true sum -> flip probability ~1e-7.

#define B_DIM 64
#define IN_DIM 1024
#define OUT_DIM 1024
#define T_DIM 256

#define BM 64
#define BN 64
#define BK 16
#define LDP 72   // LDS row pitch (floats): 72*4=288B, multiple of 16B for b128

__global__ __launch_bounds__(256) void spk_gemm_f64_kernel(
    const float* __restrict__ x,    // [B, IN, T]
    const float* __restrict__ W,    // [OUT, IN]
    float* __restrict__ syn_hi,     // [B, OUT, T] = d_out
    float* __restrict__ syn_lo)     // [B, OUT, T] = d_ws (may be null)
{
    const int tid = threadIdx.x;
    const int tb = blockIdx.x;   // t tile: 0..3
    const int ob = blockIdx.y;   // o tile: 0..15
    const int b  = blockIdx.z;   // batch:  0..63

    __shared__ __align__(16) float As[BK][LDP];  // W tile, [k][o]
    __shared__ __align__(16) float Bs[BK][LDP];  // x tile, [k][t]

    const int o0 = ob * BM;
    const int t0 = tb * BN;

    const float* Wp = W + (size_t)o0 * IN_DIM;
    const float* xp = x + (size_t)b * IN_DIM * T_DIM + t0;

    double acc[4][4] = {};

    const int ro = (tid / 16) * 4;   // micro-tile row (o), mult of 4
    const int co = (tid % 16) * 4;   // micro-tile col (t), mult of 4

    // A-tile load indices: one float4 of W per thread (1024 elems / 256 thr)
    const int ar = tid / 4;          // o row within tile, 0..63
    const int ac = (tid % 4) * 4;    // k col within tile, {0,4,8,12}
    // B-tile: one float4 of x per thread
    const int bkr = tid / 16;        // k row within tile, 0..15
    const int btc = (tid % 16) * 4;  // t col within tile, mult of 4

    for (int k0 = 0; k0 < IN_DIM; k0 += BK) {
        float4 w4 = *(const float4*)&Wp[(size_t)ar * IN_DIM + k0 + ac];
        As[ac + 0][ar] = w4.x;       // transposed scatter (4-way bank, rare)
        As[ac + 1][ar] = w4.y;
        As[ac + 2][ar] = w4.z;
        As[ac + 3][ar] = w4.w;
        *(float4*)&Bs[bkr][btc] =
            *(const float4*)&xp[(size_t)(k0 + bkr) * T_DIM + btc];
        __syncthreads();

        #pragma unroll
        for (int kk = 0; kk < BK; ++kk) {
            float4 a4 = *(const float4*)&As[kk][ro];
            float4 b4 = *(const float4*)&Bs[kk][co];
            double a[4] = {(double)a4.x, (double)a4.y, (double)a4.z, (double)a4.w};
            double bb[4] = {(double)b4.x, (double)b4.y, (double)b4.z, (double)b4.w};
            #pragma unroll
            for (int i = 0; i < 4; ++i)
                #pragma unroll
                for (int j = 0; j < 4; ++j)
                    acc[i][j] = fma(a[i], bb[j], acc[i][j]);
        }
        __syncthreads();
    }

    float* ohi = syn_hi + ((size_t)b * OUT_DIM + o0) * T_DIM + t0;
    float* olo = syn_lo ? syn_lo + ((size_t)b * OUT_DIM + o0) * T_DIM + t0 : nullptr;
    #pragma unroll
    for (int i = 0; i < 4; ++i)
        #pragma unroll
        for (int j = 0; j < 4; ++j) {
            double s = acc[i][j];
            float hi = (float)s;
            ohi[(size_t)(ro + i) * T_DIM + co + j] = hi;
            if (olo) {
                float lo = (float)(s - (double)hi);
                olo[(size_t)(ro + i) * T_DIM + co + j] = lo;
            }
        }
}

// In-place over hi: hi holds syn_hi on entry, f32 spikes on exit.
// f64 LIF: reset = (mem > 1); mem = 0.9*mem + (hi+lo) - reset; spk = (mem-1 > 0)
__global__ __launch_bounds__(256) void spk_scan_f64_kernel(
    float* __restrict__ hi, const float* __restrict__ lo)
{
    const int TC = 16;
    __shared__ float thi[256][TC + 1];
    __shared__ float tlo[256][TC + 1];

    const int tid = threadIdx.x;
    const size_t row0 = (size_t)blockIdx.x * 256;

    double mem = 0.0;
    for (int t0 = 0; t0 < T_DIM; t0 += TC) {
        // 256 rows x 16 cols = 1024 float4 slots / 256 threads = 4 each
        #pragma unroll
        for (int p = 0; p < 4; ++p) {
            int id = tid + p * 256;
            int r = id / 4;                // 4 float4 per row
            int c = (id % 4) * 4;
            size_t g = (row0 + r) * T_DIM + t0 + c;
            float4 vh = *(const float4*)&hi[g];
            thi[r][c] = vh.x; thi[r][c+1] = vh.y; thi[r][c+2] = vh.z; thi[r][c+3] = vh.w;
            if (lo) {
                float4 vl = *(const float4*)&lo[g];
                tlo[r][c] = vl.x; tlo[r][c+1] = vl.y; tlo[r][c+2] = vl.z; tlo[r][c+3] = vl.w;
            }
        }
        __syncthreads();

        float spk[TC];
        #pragma unroll
        for (int t = 0; t < TC; ++t) {
            double s = (double)thi[tid][t];
            if (lo) s += (double)tlo[tid][t];
            double reset = (mem > 1.0) ? 1.0 : 0.0;
            mem = 0.9 * mem + s - reset;
            spk[t] = ((mem - 1.0) > 0.0) ? 1.0f : 0.0f;
        }
        __syncthreads();

        #pragma unroll
        for (int t = 0; t < TC; ++t) thi[tid][t] = spk[t];
        __syncthreads();

        #pragma unroll
        for (int p = 0; p < 4; ++p) {
            int id = tid + p * 256;
            int r = id / 4;
            int c = (id % 4) * 4;
            float4 v = make_float4(thi[r][c], thi[r][c+1], thi[r][c+2], thi[r][c+3]);
            *(float4*)&hi[(row0 + r) * T_DIM + t0 + c] = v;
        }
        __syncthreads();
    }
}

extern "C" void kernel_launch(void* const* d_in, const int* in_sizes, int n_in,
                              void* d_out, int out_size, void* d_ws, size_t ws_size,
                              hipStream_t stream)
{
    const float* x = (const float*)d_in[0];   // [64, 1024, 256]
    const float* W = (const float*)d_in[1];   // [1024, 1024]
    float* hi = (float*)d_out;                // [64, 1024, 256]

    const size_t need = (size_t)B_DIM * OUT_DIM * T_DIM * sizeof(float); // 67 MB
    float* lo = (ws_size >= need) ? (float*)d_ws : nullptr;

    dim3 ggrid(T_DIM / BN, OUT_DIM / BM, B_DIM);  // (4, 16, 64)
    spk_gemm_f64_kernel<<<ggrid, dim3(256), 0, stream>>>(x, W, hi, lo);

    dim3 sgrid((B_DIM * OUT_DIM) / 256);          // 256 blocks
    spk_scan_f64_kernel<<<sgrid, dim3(256), 0, stream>>>(hi, lo);
}

// Round 3
// 819.505 us; speedup vs baseline: 1.1532x; 1.1532x over previous
//
#include <hip/hip_runtime.h>

// B=64, IN=1024, OUT=1024, T=256
// syn[b,o,t] = sum_i W[o,i] * x[b,i,t]  -- f64 accumulation (exact products),
// stored as double-f32 (hi in d_out, lo in d_ws). f64 LIF scan -> f32 spikes.
//
// R2: 128x128 block tile, 8x8 f64 micro-tile per thread (128 acc VGPRs).
// Per k-step: 64 v_fma_f64 vs 16 cvt + 4 ds_read_b128 -> FMA ~84% of VALU
// (was 56% with 4x4). Predicted GEMM ~520 us at ~66 TF f64.

#define B_DIM 64
#define IN_DIM 1024
#define OUT_DIM 1024
#define T_DIM 256

#define BM 128   // o
#define BN 128   // t
#define BK 16    // k
#define LDP 132  // LDS row pitch in floats (128 + 4, multiple of 4 for b128)

__global__ __launch_bounds__(256, 2) void spk_gemm_f64_kernel(
    const float* __restrict__ x,    // [B, IN, T]
    const float* __restrict__ W,    // [OUT, IN]
    float* __restrict__ syn_hi,     // [B, OUT, T] = d_out
    float* __restrict__ syn_lo)     // [B, OUT, T] = d_ws
{
    const int tid = threadIdx.x;
    const int tb = blockIdx.x;   // t tile: 0..1
    const int ob = blockIdx.y;   // o tile: 0..7
    const int b  = blockIdx.z;   // batch:  0..63

    __shared__ __align__(16) float As[BK][LDP];  // W tile, [k][o]
    __shared__ __align__(16) float Bs[BK][LDP];  // x tile, [k][t]

    const int o0 = ob * BM;
    const int t0 = tb * BN;

    const float* Wp = W + (size_t)o0 * IN_DIM;
    const float* xp = x + (size_t)b * IN_DIM * T_DIM + t0;

    double acc[8][8] = {};

    const int ro = (tid / 16) * 8;   // micro-tile row (o): 0..120
    const int co = (tid % 16) * 8;   // micro-tile col (t): 0..120

    // A staging: 128 rows x 16 k = 2048 f32 = 512 float4 -> 2 per thread
    //   slot id: r = id/4 (o row), c = (id%4)*4 (k col)
    // B staging: 16 k x 128 t = 2048 f32 = 512 float4 -> 2 per thread
    //   slot id: kr = id/32, tc = (id%32)*4

    for (int k0 = 0; k0 < IN_DIM; k0 += BK) {
        #pragma unroll
        for (int p = 0; p < 2; ++p) {
            int id = tid + p * 256;
            int r = id / 4;
            int c = (id % 4) * 4;
            float4 w4 = *(const float4*)&Wp[(size_t)r * IN_DIM + k0 + c];
            As[c + 0][r] = w4.x;
            As[c + 1][r] = w4.y;
            As[c + 2][r] = w4.z;
            As[c + 3][r] = w4.w;

            int kr = id / 32;
            int tc = (id % 32) * 4;
            *(float4*)&Bs[kr][tc] =
                *(const float4*)&xp[(size_t)(k0 + kr) * T_DIM + tc];
        }
        __syncthreads();

        #pragma unroll
        for (int kk = 0; kk < BK; ++kk) {
            float4 a4lo = *(const float4*)&As[kk][ro];
            float4 a4hi = *(const float4*)&As[kk][ro + 4];
            float4 b4lo = *(const float4*)&Bs[kk][co];
            float4 b4hi = *(const float4*)&Bs[kk][co + 4];
            double a[8] = {(double)a4lo.x, (double)a4lo.y, (double)a4lo.z, (double)a4lo.w,
                           (double)a4hi.x, (double)a4hi.y, (double)a4hi.z, (double)a4hi.w};
            double bb[8] = {(double)b4lo.x, (double)b4lo.y, (double)b4lo.z, (double)b4lo.w,
                            (double)b4hi.x, (double)b4hi.y, (double)b4hi.z, (double)b4hi.w};
            #pragma unroll
            for (int i = 0; i < 8; ++i)
                #pragma unroll
                for (int j = 0; j < 8; ++j)
                    acc[i][j] = fma(a[i], bb[j], acc[i][j]);
        }
        __syncthreads();
    }

    float* ohi = syn_hi + ((size_t)b * OUT_DIM + o0) * T_DIM + t0;
    float* olo = syn_lo + ((size_t)b * OUT_DIM + o0) * T_DIM + t0;
    #pragma unroll
    for (int i = 0; i < 8; ++i) {
        #pragma unroll
        for (int j = 0; j < 8; ++j) {
            double s = acc[i][j];
            float hi = (float)s;
            float lo = (float)(s - (double)hi);
            ohi[(size_t)(ro + i) * T_DIM + co + j] = hi;
            olo[(size_t)(ro + i) * T_DIM + co + j] = lo;
        }
    }
}

// In-place over hi: hi holds syn_hi on entry, f32 spikes on exit.
// f64 LIF: reset = (mem > 1); mem = 0.9*mem + (hi+lo) - reset; spk = (mem-1 > 0)
__global__ __launch_bounds__(256) void spk_scan_f64_kernel(
    float* __restrict__ hi, const float* __restrict__ lo)
{
    const int TC = 16;
    __shared__ float thi[256][TC + 1];
    __shared__ float tlo[256][TC + 1];

    const int tid = threadIdx.x;
    const size_t row0 = (size_t)blockIdx.x * 256;

    double mem = 0.0;
    for (int t0 = 0; t0 < T_DIM; t0 += TC) {
        #pragma unroll
        for (int p = 0; p < 4; ++p) {
            int id = tid + p * 256;
            int r = id / 4;
            int c = (id % 4) * 4;
            size_t g = (row0 + r) * T_DIM + t0 + c;
            float4 vh = *(const float4*)&hi[g];
            thi[r][c] = vh.x; thi[r][c+1] = vh.y; thi[r][c+2] = vh.z; thi[r][c+3] = vh.w;
            float4 vl = *(const float4*)&lo[g];
            tlo[r][c] = vl.x; tlo[r][c+1] = vl.y; tlo[r][c+2] = vl.z; tlo[r][c+3] = vl.w;
        }
        __syncthreads();

        float spk[TC];
        #pragma unroll
        for (int t = 0; t < TC; ++t) {
            double s = (double)thi[tid][t] + (double)tlo[tid][t];
            double reset = (mem > 1.0) ? 1.0 : 0.0;
            mem = 0.9 * mem + s - reset;
            spk[t] = ((mem - 1.0) > 0.0) ? 1.0f : 0.0f;
        }
        __syncthreads();

        #pragma unroll
        for (int t = 0; t < TC; ++t) thi[tid][t] = spk[t];
        __syncthreads();

        #pragma unroll
        for (int p = 0; p < 4; ++p) {
            int id = tid + p * 256;
            int r = id / 4;
            int c = (id % 4) * 4;
            float4 v = make_float4(thi[r][c], thi[r][c+1], thi[r][c+2], thi[r][c+3]);
            *(float4*)&hi[(row0 + r) * T_DIM + t0 + c] = v;
        }
        __syncthreads();
    }
}

extern "C" void kernel_launch(void* const* d_in, const int* in_sizes, int n_in,
                              void* d_out, int out_size, void* d_ws, size_t ws_size,
                              hipStream_t stream)
{
    const float* x = (const float*)d_in[0];   // [64, 1024, 256]
    const float* W = (const float*)d_in[1];   // [1024, 1024]
    float* hi = (float*)d_out;                // [64, 1024, 256]
    float* lo = (float*)d_ws;                 // 67 MB of ws

    dim3 ggrid(T_DIM / BN, OUT_DIM / BM, B_DIM);  // (2, 8, 64)
    spk_gemm_f64_kernel<<<ggrid, dim3(256), 0, stream>>>(x, W, hi, lo);

    dim3 sgrid((B_DIM * OUT_DIM) / 256);          // 256 blocks
    spk_scan_f64_kernel<<<sgrid, dim3(256), 0, stream>>>(hi, lo);
}